// Round 5
// baseline (884.611 us; speedup 1.0000x reference)
//
#include <hip/hip_runtime.h>
#include <hip/hip_bf16.h>
#include <math.h>

#define NFEAT 512
#define HID   64
#define NCLS  40
#define T2STRIDE 64             // t2 rows padded to 128B (one cache line)

typedef __attribute__((ext_vector_type(8))) short bf16x8v;   // 8 bf16 = 4 VGPR
typedef __attribute__((ext_vector_type(4))) float f32x4v;    // MFMA acc
typedef __attribute__((ext_vector_type(4))) int   v4i;
typedef __attribute__((ext_vector_type(4))) float v4f;

__device__ __forceinline__ float rl_f(float v, int l) {
    return __int_as_float(__builtin_amdgcn_readlane(__float_as_int(v), l));
}
__device__ __forceinline__ unsigned short f2bf(float f) {
    __hip_bfloat16 h = __float2bfloat16(f);
    return *(unsigned short*)&h;
}

// ---------------- CSR build: direct global-atomic (replaces staged binning) ----------------
// deg/cursor are 400KB tables -> L2-resident; ei streamed with nontemporal loads
// so the stream does not evict them (round-4 lesson: streams flush hot tables).

__global__ __launch_bounds__(256) void deg_count(const int* __restrict__ ei, int e,
                                                 int* __restrict__ deg) {
    int i4 = (blockIdx.x * 256 + threadIdx.x) * 4;
    if (i4 + 3 < e) {
        v4i d = __builtin_nontemporal_load((const v4i*)(ei + e + i4));
        atomicAdd(&deg[d.x], 1);
        atomicAdd(&deg[d.y], 1);
        atomicAdd(&deg[d.z], 1);
        atomicAdd(&deg[d.w], 1);
    } else {
        for (int i = i4; i < e; i++) atomicAdd(&deg[ei[e + i]], 1);
    }
}

__global__ __launch_bounds__(256) void deg_bsum(const int* __restrict__ deg, int n,
                                                int* __restrict__ bsum) {
    __shared__ int red[256];
    int idx = blockIdx.x * 256 + threadIdx.x;
    red[threadIdx.x] = (idx < n) ? deg[idx] : 0;
    __syncthreads();
    #pragma unroll
    for (int off = 128; off; off >>= 1) {
        if (threadIdx.x < off) red[threadIdx.x] += red[threadIdx.x + off];
        __syncthreads();
    }
    if (threadIdx.x == 0) bsum[blockIdx.x] = red[0];
}

// each block redundantly computes its base from bsum (no extra launch / dependency)
__global__ __launch_bounds__(256) void scan_emit(const int* __restrict__ deg,
                                                 const int* __restrict__ bsum,
                                                 int n, int e,
                                                 int* __restrict__ row_ptr,
                                                 int* __restrict__ cursor,
                                                 float* __restrict__ dinv) {
    __shared__ int partial[256];
    __shared__ int sc[256];
    int b = blockIdx.x, t = threadIdx.x;
    int p = 0;
    for (int i = t; i < b; i += 256) p += bsum[i];
    partial[t] = p;
    __syncthreads();
    #pragma unroll
    for (int off = 128; off; off >>= 1) {
        if (t < off) partial[t] += partial[t + off];
        __syncthreads();
    }
    int base = partial[0];
    int idx = b * 256 + t;
    int d = (idx < n) ? deg[idx] : 0;
    sc[t] = d;
    __syncthreads();
    #pragma unroll
    for (int off = 1; off < 256; off <<= 1) {
        int u = (t >= off) ? sc[t - off] : 0;
        __syncthreads();
        sc[t] += u;
        __syncthreads();
    }
    if (idx < n) {
        int rp = base + sc[t] - d;   // exclusive prefix
        row_ptr[idx] = rp;
        cursor[idx] = rp;
        dinv[idx] = rsqrtf((float)(d + 1));
    }
    if (b == 0 && t == 0) row_ptr[n] = e;
}

__global__ __launch_bounds__(256) void fill_col(const int* __restrict__ ei, int e,
                                                int* __restrict__ cursor,
                                                int* __restrict__ col) {
    int i4 = (blockIdx.x * 256 + threadIdx.x) * 4;
    if (i4 + 3 < e) {
        v4i s = __builtin_nontemporal_load((const v4i*)(ei + i4));
        v4i d = __builtin_nontemporal_load((const v4i*)(ei + e + i4));
        int p0 = atomicAdd(&cursor[d.x], 1); col[p0] = s.x;
        int p1 = atomicAdd(&cursor[d.y], 1); col[p1] = s.y;
        int p2 = atomicAdd(&cursor[d.z], 1); col[p2] = s.z;
        int p3 = atomicAdd(&cursor[d.w], 1); col[p3] = s.w;
    } else {
        for (int i = i4; i < e; i++) {
            int p = atomicAdd(&cursor[ei[e + i]], 1);
            col[p] = ei[i];
        }
    }
}

// ---------------- one-time: W1 -> bf16, transposed [64][512] ----------------

__global__ __launch_bounds__(256) void w1_to_bf16t(const float* __restrict__ W1,
                                                   unsigned short* __restrict__ w1bt) {
    int idx = blockIdx.x * 256 + threadIdx.x;   // 64*512 = 32768
    int c = idx >> 9, k = idx & 511;
    w1bt[idx] = f2bf(W1[k * HID + c]);
}

// ---------------- GEMM1 (MFMA): t1 = bf16( dinv[:,None] * (x @ W1) ) ----------------
// Fragment layout (m89/m91-verified): A row=lane&15, k=8*(lane>>4)+j;
// B col=lane&15, same k; C/D col=lane&15, row=4*(lane>>4)+reg.

__global__ __launch_bounds__(256) void gemm1(const float* __restrict__ x,
                                             const unsigned short* __restrict__ w1bt,
                                             const float* __restrict__ dinv,
                                             __hip_bfloat16* __restrict__ t1, int n) {
    __shared__ __align__(16) unsigned short As[64][40];  // [row][k], pad 40
    __shared__ __align__(16) unsigned short Bs[64][40];  // [col][k], pad 40
    int t = threadIdx.x;
    int m0 = blockIdx.x * 64;
    int w = t >> 6, lane = t & 63;
    int lrow = lane & 15, lkg = lane >> 4;
    f32x4v acc[4] = {};

    int arow = t >> 2;        // staging row / col (0..63)
    int akg = t & 3;          // k-group of 8
    int grow = m0 + arow; if (grow >= n) grow = n - 1;
    const float* xrow = x + (size_t)grow * NFEAT;

    for (int k0 = 0; k0 < NFEAT; k0 += 32) {
        v4f v0 = __builtin_nontemporal_load((const v4f*)(xrow + k0 + akg * 8));
        v4f v1 = __builtin_nontemporal_load((const v4f*)(xrow + k0 + akg * 8 + 4));
        union { unsigned short u[8]; uint4 q; } P;
        P.u[0] = f2bf(v0.x); P.u[1] = f2bf(v0.y); P.u[2] = f2bf(v0.z); P.u[3] = f2bf(v0.w);
        P.u[4] = f2bf(v1.x); P.u[5] = f2bf(v1.y); P.u[6] = f2bf(v1.z); P.u[7] = f2bf(v1.w);
        *(uint4*)&As[arow][akg * 8] = P.q;
        *(uint4*)&Bs[arow][akg * 8] = *(const uint4*)(w1bt + arow * 512 + k0 + akg * 8);
        __syncthreads();
        bf16x8v af = *(const bf16x8v*)&As[w * 16 + lrow][lkg * 8];
        #pragma unroll
        for (int nb = 0; nb < 4; nb++) {
            bf16x8v bfv = *(const bf16x8v*)&Bs[nb * 16 + lrow][lkg * 8];
            acc[nb] = __builtin_amdgcn_mfma_f32_16x16x32_bf16(af, bfv, acc[nb], 0, 0, 0);
        }
        __syncthreads();
    }
    #pragma unroll
    for (int r = 0; r < 4; r++) {
        int row = m0 + w * 16 + lkg * 4 + r;
        if (row < n) {
            float d = dinv[row];
            #pragma unroll
            for (int nb = 0; nb < 4; nb++) {
                t1[(size_t)row * HID + nb * 16 + lrow] = __float2bfloat16(acc[nb][r] * d);
            }
        }
    }
}

// ---------------- fused agg1 + gemm2 ----------------
// 8 lanes per 128B row (dwordx4/lane) -> 8 edges per VMEM instruction, depth-4
// (32 edges, 4KB in flight/wave). ds_bpermute index broadcast; zero sentinel row t1[n].
// col read nontemporally: stream must not evict the hot 12.8MB t1 table from L2.
// GEMM2 via v_readlane broadcasts (VALU, not DS) + 32 LDS float2 reads/node.

#define UNPACK_ADD(pv) do { \
    acc[0] += __uint_as_float((pv).x << 16); acc[1] += __uint_as_float((pv).x & 0xffff0000u); \
    acc[2] += __uint_as_float((pv).y << 16); acc[3] += __uint_as_float((pv).y & 0xffff0000u); \
    acc[4] += __uint_as_float((pv).z << 16); acc[5] += __uint_as_float((pv).z & 0xffff0000u); \
    acc[6] += __uint_as_float((pv).w << 16); acc[7] += __uint_as_float((pv).w & 0xffff0000u); } while (0)

__global__ __launch_bounds__(256) void agg1_gemm2(const __hip_bfloat16* __restrict__ t1,
                                                  const int* __restrict__ row_ptr,
                                                  const int* __restrict__ col,
                                                  const float* __restrict__ dinv,
                                                  const float* __restrict__ b1,
                                                  const float* __restrict__ W2,
                                                  __hip_bfloat16* __restrict__ t2, int n) {
    __shared__ float2 w2p[32 * 40];   // [k/2][c] float2 = {W2[2k'][c], W2[2k'+1][c]}
    for (int i = threadIdx.x; i < 32 * 40; i += 256) {
        int k2 = i / 40, c = i - k2 * 40;
        w2p[i] = make_float2(W2[(2 * k2) * 40 + c], W2[(2 * k2 + 1) * 40 + c]);
    }
    __syncthreads();

    int wave = threadIdx.x >> 6;
    int lane = threadIdx.x & 63;
    int node0 = blockIdx.x * 4 + wave;
    int node = (node0 < n) ? node0 : n - 1;   // clamp; store masked at end
    int r = lane & 7;                          // 16B chunk within row (feats 8r..8r+7)
    int slot = lane >> 3;                      // edge slot within 8-edge group

    const uint4* t1q = (const uint4*)t1;       // row = 8 uint4
    int s0 = row_ptr[node], s1 = row_ptr[node + 1];

    float acc[8] = {0.f, 0.f, 0.f, 0.f, 0.f, 0.f, 0.f, 0.f};

    // self loop: slot 0 only (r == lane for lane < 8)
    if (lane < 8) {
        uint4 pv = t1q[(size_t)node * 8 + lane];
        UNPACK_ADD(pv);
    }

    int bpbase = slot * 4;                     // bpermute byte index base
    for (int jb = s0; jb < s1; jb += 32) {
        int rem = s1 - jb;
        int ll = lane & 31;
        int cidx = __builtin_nontemporal_load(col + jb + ((ll < rem) ? ll : 0));
        int srcg[4];
        #pragma unroll
        for (int g = 0; g < 4; g++) {
            int src = __builtin_amdgcn_ds_bpermute(bpbase + 32 * g, cidx);
            srcg[g] = (8 * g + slot < rem) ? src : n;   // sentinel -> zero row
        }
        uint4 pv[4];
        #pragma unroll
        for (int g = 0; g < 4; g++) pv[g] = t1q[(size_t)srcg[g] * 8 + r];
        #pragma unroll
        for (int g = 0; g < 4; g++) { UNPACK_ADD(pv[g]); }
    }

    // cross-slot butterfly: every lane ends with full sums for feats 8r..8r+7
    #pragma unroll
    for (int off = 8; off < 64; off <<= 1) {
        #pragma unroll
        for (int j = 0; j < 8; j++) acc[j] += __shfl_xor(acc[j], off, 64);
    }

    float dn = dinv[node];
    const float4* b1q = (const float4*)b1;
    float4 ba = b1q[2 * r];
    float4 bb = b1q[2 * r + 1];
    float hv[8];
    hv[0] = fmaxf(0.f, dn * acc[0] + ba.x);
    hv[1] = fmaxf(0.f, dn * acc[1] + ba.y);
    hv[2] = fmaxf(0.f, dn * acc[2] + ba.z);
    hv[3] = fmaxf(0.f, dn * acc[3] + ba.w);
    hv[4] = fmaxf(0.f, dn * acc[4] + bb.x);
    hv[5] = fmaxf(0.f, dn * acc[5] + bb.y);
    hv[6] = fmaxf(0.f, dn * acc[6] + bb.z);
    hv[7] = fmaxf(0.f, dn * acc[7] + bb.w);

    int c = (lane < 40) ? lane : 39;
    float o = 0.0f;
    #pragma unroll
    for (int rr = 0; rr < 8; rr++) {
        #pragma unroll
        for (int j2 = 0; j2 < 4; j2++) {
            float ha = rl_f(hv[2 * j2],     rr);   // h[8rr + 2j2]
            float hb = rl_f(hv[2 * j2 + 1], rr);   // h[8rr + 2j2+1]
            float2 wv = w2p[(4 * rr + j2) * 40 + c];
            o += ha * wv.x + hb * wv.y;
        }
    }
    if (node0 < n && lane < 40)
        t2[(size_t)node * T2STRIDE + lane] = __float2bfloat16(dn * o);
}

// ---------------- agg2 + bias + softmax ----------------
// t2 rows padded to 128B: each random gather touches exactly 1 cache line.
// col read nontemporally (protect the hot t2 table in L2).

__global__ __launch_bounds__(256) void agg2_softmax(const __hip_bfloat16* __restrict__ t2,
                                                    const int* __restrict__ row_ptr,
                                                    const int* __restrict__ col,
                                                    const float* __restrict__ dinv,
                                                    const float* __restrict__ b2,
                                                    float* __restrict__ out, int n) {
    int wave = threadIdx.x >> 6;
    int lane = threadIdx.x & 63;
    int node = blockIdx.x * 4 + wave;
    if (node >= n) return;
    int h = lane >> 5;                 // which edge of the pair
    int p = lane & 31;                 // class-pair index
    int pc = (p < 20) ? p : 19;        // clamped (lanes 20-31 dead weight)
    const unsigned* t2d = (const unsigned*)t2;   // padded row = 32 dwords
    int s0 = row_ptr[node], s1 = row_ptr[node + 1];

    float ax = 0.f, ay = 0.f;
    if (h == 0) {                      // self loop counted once
        unsigned v = t2d[(size_t)node * 32 + pc];
        ax = __uint_as_float(v << 16);
        ay = __uint_as_float(v & 0xffff0000u);
    }
    for (int jb = s0; jb < s1; jb += 16) {
        int rem = s1 - jb;
        int cv = __builtin_nontemporal_load(col + jb + ((lane < rem) ? lane : 0));
        int srcg[8];
        #pragma unroll
        for (int i = 0; i < 8; i++) {
            int eid = 2 * i + h;
            int src = __builtin_amdgcn_ds_bpermute(4 * eid, cv);
            srcg[i] = (eid < rem) ? src : n;           // sentinel -> zero row
        }
        unsigned pv[8];
        #pragma unroll
        for (int i = 0; i < 8; i++) pv[i] = t2d[(size_t)srcg[i] * 32 + pc];
        #pragma unroll
        for (int i = 0; i < 8; i++) {
            ax += __uint_as_float(pv[i] << 16);
            ay += __uint_as_float(pv[i] & 0xffff0000u);
        }
    }
    ax += __shfl_xor(ax, 32, 64);
    ay += __shfl_xor(ay, 32, 64);

    float dn = dinv[node];
    float2 bv = *(const float2*)(b2 + 2 * pc);
    float lx = dn * ax + bv.x;
    float ly = dn * ay + bv.y;
    float m = (p < 20) ? fmaxf(lx, ly) : -INFINITY;
    #pragma unroll
    for (int off = 16; off; off >>= 1) m = fmaxf(m, __shfl_xor(m, off, 64));
    float ex = (p < 20) ? expf(lx - m) : 0.0f;
    float ey = (p < 20) ? expf(ly - m) : 0.0f;
    float ssum = ex + ey;
    #pragma unroll
    for (int off = 16; off; off >>= 1) ssum += __shfl_xor(ssum, off, 64);
    if (h == 0 && p < 20) {
        *(float2*)(out + (size_t)node * NCLS + 2 * p) = make_float2(ex / ssum, ey / ssum);
    }
}

// ---------------- launch ----------------

static inline size_t align256(size_t x) { return (x + 255) & ~(size_t)255; }

extern "C" void kernel_launch(void* const* d_in, const int* in_sizes, int n_in,
                              void* d_out, int out_size, void* d_ws, size_t ws_size,
                              hipStream_t stream) {
    const float* x  = (const float*)d_in[0];
    const int*   ei = (const int*)d_in[1];
    const float* W1 = (const float*)d_in[2];
    const float* b1 = (const float*)d_in[3];
    const float* W2 = (const float*)d_in[4];
    const float* b2 = (const float*)d_in[5];
    float* out = (float*)d_out;

    const int n = in_sizes[0] / NFEAT;      // 100000
    const int e = in_sizes[1] / 2;          // 3200000

    char* ws = (char*)d_ws;
    size_t off = 0;
    int*   row_ptr  = (int*)(ws + off);   off += align256((size_t)(n + 1) * 4);
    float* dinv     = (float*)(ws + off); off += align256((size_t)n * 4);
    int*   deg      = (int*)(ws + off);   off += align256((size_t)n * 4);
    int*   cursor   = (int*)(ws + off);   off += align256((size_t)n * 4);
    int*   bsum     = (int*)(ws + off);   off += align256(512 * 4);
    int*   col      = (int*)(ws + off);   off += align256((size_t)e * 4);
    unsigned short* w1bt = (unsigned short*)(ws + off); off += align256((size_t)HID * NFEAT * 2);
    __hip_bfloat16* t1 = (__hip_bfloat16*)(ws + off); off += align256((size_t)(n + 1) * HID * 2);
    __hip_bfloat16* t2 = (__hip_bfloat16*)(ws + off); off += align256((size_t)(n + 1) * T2STRIDE * 2);

    const int nb256 = (n + 255) / 256;                 // 391
    const int eb4   = (e / 4 + 255) / 256;             // 3125

    (void)hipMemsetAsync(deg, 0, (size_t)n * 4, stream);
    (void)hipMemsetAsync(t1 + (size_t)n * HID, 0, HID * 2, stream);           // sentinel zero row
    (void)hipMemsetAsync(t2 + (size_t)n * T2STRIDE, 0, T2STRIDE * 2, stream); // sentinel zero row
    w1_to_bf16t<<<(HID * NFEAT) / 256, 256, 0, stream>>>(W1, w1bt);
    deg_count<<<eb4, 256, 0, stream>>>(ei, e, deg);
    deg_bsum<<<nb256, 256, 0, stream>>>(deg, n, bsum);
    scan_emit<<<nb256, 256, 0, stream>>>(deg, bsum, n, e, row_ptr, cursor, dinv);
    fill_col<<<eb4, 256, 0, stream>>>(ei, e, cursor, col);
    gemm1<<<(n + 63) / 64, 256, 0, stream>>>(x, w1bt, dinv, t1, n);
    agg1_gemm2<<<(n + 3) / 4, 256, 0, stream>>>(t1, row_ptr, col, dinv, b1, W2, t2, n);
    agg2_softmax<<<(n + 3) / 4, 256, 0, stream>>>(t2, row_ptr, col, dinv, b2, out, n);
}

// Round 6
// 714.970 us; speedup vs baseline: 1.2373x; 1.2373x over previous
//
#include <hip/hip_runtime.h>
#include <hip/hip_bf16.h>
#include <math.h>

#define NFEAT 512
#define HID   64
#define NCLS  40
#define NPW   4                 // nodes per wave in agg_pass

#define BSHIFT 9
#define BSIZE  512              // nodes per bucket
#define BCAP   20480            // staged edges per bucket (avg ~16.3K, sd ~128)
#define CHUNK  4096             // edges per bin_scatter block

typedef __attribute__((ext_vector_type(8))) short bf16x8v;   // 8 bf16 = 4 VGPR
typedef __attribute__((ext_vector_type(4))) float f32x4v;    // MFMA acc / nt store
typedef __attribute__((ext_vector_type(2))) float f32x2v;
typedef __attribute__((ext_vector_type(4))) float v4f;

__device__ __forceinline__ float rl_f(float v, int l) {
    return __int_as_float(__builtin_amdgcn_readlane(__float_as_int(v), l));
}
__device__ __forceinline__ unsigned short f2bf(float f) {
    __hip_bfloat16 h = __float2bfloat16(f);
    return *(unsigned short*)&h;
}

// ---------------- CSR build: two-level binning (R3-proven; R5's atomic build regressed 6x) ----------------

__global__ __launch_bounds__(256) void bin_scatter(const int* __restrict__ ei, int e,
                                                   int nbuckets,
                                                   int* __restrict__ bucket_cursor,
                                                   int* __restrict__ stage) {
    __shared__ int packed_s[CHUNK];
    __shared__ unsigned char bkt_s[CHUNK];
    __shared__ int hist[256];
    __shared__ int base_s[256];
    __shared__ int lcur[256];
    int t = threadIdx.x;
    int b0 = blockIdx.x * CHUNK;
    int cnt = min(CHUNK, e - b0);
    for (int i = t; i < 256; i += 256) hist[i] = 0;
    __syncthreads();
    for (int i = t; i < cnt; i += 256) {
        int s = __builtin_nontemporal_load(ei + b0 + i);
        int d = __builtin_nontemporal_load(ei + e + b0 + i);
        packed_s[i] = (s << BSHIFT) | (d & (BSIZE - 1));
        bkt_s[i] = (unsigned char)(d >> BSHIFT);
        atomicAdd(&hist[d >> BSHIFT], 1);
    }
    __syncthreads();
    for (int i = t; i < nbuckets; i += 256) {
        int c = hist[i];
        base_s[i] = c ? atomicAdd(&bucket_cursor[i], c) : 0;
        lcur[i] = 0;
    }
    __syncthreads();
    for (int i = t; i < cnt; i += 256) {
        int bk = bkt_s[i];
        int pos = base_s[bk] + atomicAdd(&lcur[bk], 1);
        if (pos < BCAP) stage[(size_t)bk * BCAP + pos] = packed_s[i];
    }
}

// bucket_csr with the bucket-base scan folded in
__global__ __launch_bounds__(256) void bucket_csr(const int* __restrict__ stage,
                                                  const int* __restrict__ bucket_cursor,
                                                  int* __restrict__ row_ptr,
                                                  float* __restrict__ dinv,
                                                  int* __restrict__ col,
                                                  int n, int e, int nbuckets) {
    __shared__ int sc[256];
    __shared__ int hist[BSIZE];
    __shared__ int lbase[BSIZE];
    __shared__ int psum[256];
    int b = blockIdx.x;
    int t = threadIdx.x;
    int v = (t < nbuckets) ? bucket_cursor[t] : 0;
    sc[t] = v;
    __syncthreads();
    #pragma unroll
    for (int off = 1; off < 256; off <<= 1) {
        int u = (t >= off) ? sc[t - off] : 0;
        __syncthreads();
        sc[t] += u;
        __syncthreads();
    }
    int base0 = (b > 0) ? sc[b - 1] : 0;
    if (b == 0 && t == 0) row_ptr[n] = e;

    int cnt = min(bucket_cursor[b], BCAP);
    int node0 = b << BSHIFT;
    int nnodes = min(BSIZE, n - node0);
    const int* st = stage + (size_t)b * BCAP;
    for (int i = t; i < BSIZE; i += 256) hist[i] = 0;
    __syncthreads();
    for (int i = t; i < cnt; i += 256) atomicAdd(&hist[st[i] & (BSIZE - 1)], 1);
    __syncthreads();
    int h0 = hist[2 * t], h1 = hist[2 * t + 1];
    int pair = h0 + h1;
    psum[t] = pair;
    __syncthreads();
    #pragma unroll
    for (int off = 1; off < 256; off <<= 1) {
        int u = (t >= off) ? psum[t - off] : 0;
        __syncthreads();
        psum[t] += u;
        __syncthreads();
    }
    int ex = psum[t] - pair;
    lbase[2 * t] = ex;
    lbase[2 * t + 1] = ex + h0;
    __syncthreads();
    for (int i = t; i < nnodes; i += 256) {
        row_ptr[node0 + i] = base0 + lbase[i];
        dinv[node0 + i] = rsqrtf((float)(hist[i] + 1));
    }
    __syncthreads();
    for (int i = t; i < cnt; i += 256) {
        int p = st[i];
        int pos = atomicAdd(&lbase[p & (BSIZE - 1)], 1);
        col[base0 + pos] = ((unsigned)p) >> BSHIFT;
    }
}

// ---------------- one-time: W1 -> bf16 transposed; t1c sentinel rows ----------------

__global__ __launch_bounds__(256) void w1_to_bf16t(const float* __restrict__ W1,
                                                   unsigned short* __restrict__ w1bt,
                                                   unsigned short* __restrict__ t1c, int n) {
    int idx = blockIdx.x * 256 + threadIdx.x;   // 64*512 = 32768
    int c = idx >> 9, k = idx & 511;
    w1bt[idx] = f2bf(W1[k * HID + c]);
    if (blockIdx.x == 0 && threadIdx.x < 32) {  // zero sentinel row of each chunk
        ((unsigned*)t1c)[((size_t)(threadIdx.x >> 3) * (n + 1) + n) * 8 + (threadIdx.x & 7)] = 0;
    }
}

// ---------------- GEMM1 (MFMA): t1c = chunked bf16( dinv[:,None] * (x @ W1) ) ----------------
// t1c layout: [4 chunks][n+1 rows][16 feats] bf16 -> 32B rows, 3.2MB per chunk (< 4MB L2).

__global__ __launch_bounds__(256) void gemm1(const float* __restrict__ x,
                                             const unsigned short* __restrict__ w1bt,
                                             const float* __restrict__ dinv,
                                             unsigned short* __restrict__ t1c, int n) {
    __shared__ __align__(16) unsigned short As[64][40];  // [row][k], pad 40
    __shared__ __align__(16) unsigned short Bs[64][40];  // [col][k], pad 40
    int t = threadIdx.x;
    int m0 = blockIdx.x * 64;
    int w = t >> 6, lane = t & 63;
    int lrow = lane & 15, lkg = lane >> 4;
    f32x4v acc[4] = {};

    int arow = t >> 2;        // staging row / col (0..63)
    int akg = t & 3;          // k-group of 8
    int grow = m0 + arow; if (grow >= n) grow = n - 1;
    const float* xrow = x + (size_t)grow * NFEAT;

    for (int k0 = 0; k0 < NFEAT; k0 += 32) {
        v4f v0 = __builtin_nontemporal_load((const v4f*)(xrow + k0 + akg * 8));
        v4f v1 = __builtin_nontemporal_load((const v4f*)(xrow + k0 + akg * 8 + 4));
        union { unsigned short u[8]; uint4 q; } P;
        P.u[0] = f2bf(v0.x); P.u[1] = f2bf(v0.y); P.u[2] = f2bf(v0.z); P.u[3] = f2bf(v0.w);
        P.u[4] = f2bf(v1.x); P.u[5] = f2bf(v1.y); P.u[6] = f2bf(v1.z); P.u[7] = f2bf(v1.w);
        *(uint4*)&As[arow][akg * 8] = P.q;
        *(uint4*)&Bs[arow][akg * 8] = *(const uint4*)(w1bt + arow * 512 + k0 + akg * 8);
        __syncthreads();
        bf16x8v af = *(const bf16x8v*)&As[w * 16 + lrow][lkg * 8];
        #pragma unroll
        for (int nb = 0; nb < 4; nb++) {
            bf16x8v bfv = *(const bf16x8v*)&Bs[nb * 16 + lrow][lkg * 8];
            acc[nb] = __builtin_amdgcn_mfma_f32_16x16x32_bf16(af, bfv, acc[nb], 0, 0, 0);
        }
        __syncthreads();
    }
    #pragma unroll
    for (int r = 0; r < 4; r++) {
        int row = m0 + w * 16 + lkg * 4 + r;
        if (row < n) {
            float d = dinv[row];
            #pragma unroll
            for (int nb = 0; nb < 4; nb++) {   // col = nb*16 + lrow -> chunk nb, feat lrow
                t1c[((size_t)nb * (n + 1) + row) * 16 + lrow] = f2bf(acc[nb][r] * d);
            }
        }
    }
}

// ---------------- agg_pass v2: chunked, XCD-L2-resident gather-accumulate ----------------
// Table tc: [4][n+1][16] bf16 (32B rows, 3.2MB/chunk < 4MB XCD-L2). bid%8 -> XCD (m09):
// XCD pair {2c,2c+1} handles only chunk c, split by node halves.
// R4 failure fixes: (1) ALL streaming traffic (col loads, aggOut stores) is
// nontemporal so the stream cannot evict the resident chunk; (2) gather =
// dwordx2 x 4 lanes/row -> 16 edges per VMEM instruction (2x fewer instrs
// than the unchunked R3 kernel, 4x fewer than R4). Batch-64, sentinel tails.

__global__ __launch_bounds__(256) void agg_pass(const unsigned short* __restrict__ tc,
                                                const int* __restrict__ row_ptr,
                                                const int* __restrict__ col,
                                                float* __restrict__ aggOut,
                                                int n, int nsplit) {
    int bid = blockIdx.x;
    int xc = bid & 7;
    int chunk = xc >> 1;
    int half = xc & 1;
    int g = bid >> 3;
    int wave = threadIdx.x >> 6;
    int lane = threadIdx.x & 63;
    int part = lane & 3;          // dwordx2 within 32B row: feats 4*part..4*part+3
    int esub = lane >> 2;         // edge sub-slot 0..15
    const uint2* tcu = (const uint2*)tc + (size_t)chunk * (n + 1) * 4;
    int nodebase = g * (4 * NPW) + wave * NPW + half * nsplit;
    int nend = half ? n : nsplit;

    for (int ni = 0; ni < NPW; ni++) {
        int node = nodebase + ni;
        if (node >= nend) break;
        int s0 = row_ptr[node], s1 = row_ptr[node + 1];
        float a0 = 0.f, a1 = 0.f, a2 = 0.f, a3 = 0.f;
        if (lane < 4) {                        // self loop (esub==0, part=lane)
            uint2 v = tcu[(size_t)node * 4 + lane];
            a0 = __uint_as_float(v.x << 16);
            a1 = __uint_as_float(v.x & 0xffff0000u);
            a2 = __uint_as_float(v.y << 16);
            a3 = __uint_as_float(v.y & 0xffff0000u);
        }
        for (int jb = s0; jb < s1; jb += 64) {
            int rem = s1 - jb;
            int cv = __builtin_nontemporal_load(col + jb + ((lane < rem) ? lane : 0));
            int src[4];
            #pragma unroll
            for (int q = 0; q < 4; q++) {
                int eid = q * 16 + esub;
                int sv = __builtin_amdgcn_ds_bpermute(4 * eid, cv);
                src[q] = (eid < rem) ? sv : n;  // sentinel -> zero row
            }
            uint2 pv[4];
            #pragma unroll
            for (int q = 0; q < 4; q++) pv[q] = tcu[(size_t)src[q] * 4 + part];
            #pragma unroll
            for (int q = 0; q < 4; q++) {
                a0 += __uint_as_float(pv[q].x << 16);
                a1 += __uint_as_float(pv[q].x & 0xffff0000u);
                a2 += __uint_as_float(pv[q].y << 16);
                a3 += __uint_as_float(pv[q].y & 0xffff0000u);
            }
        }
        #pragma unroll
        for (int off = 4; off < 64; off <<= 1) {   // reduce across 16 edge-slots
            a0 += __shfl_xor(a0, off, 64);
            a1 += __shfl_xor(a1, off, 64);
            a2 += __shfl_xor(a2, off, 64);
            a3 += __shfl_xor(a3, off, 64);
        }
        if (lane < 4) {
            f32x4v o = {a0, a1, a2, a3};
            __builtin_nontemporal_store(o,
                (f32x4v*)(aggOut + (size_t)node * HID + chunk * 16 + 4 * lane));
        }
    }
}

// ---------------- finish1: g = bf16( dinv * relu(dinv*aggA + b1) ), chunked ----------------

__global__ __launch_bounds__(256) void finish1(const float* __restrict__ aggA,
                                               const float* __restrict__ dinv,
                                               const float* __restrict__ b1,
                                               unsigned short* __restrict__ gc, int n) {
    int t = threadIdx.x;
    unsigned* gcu = (unsigned*)gc;
    if (blockIdx.x == 0 && t < 32) {           // zero sentinel row of each chunk
        gcu[((size_t)(t >> 3) * (n + 1) + n) * 8 + (t & 7)] = 0;
    }
    int idx = blockIdx.x * 256 + t;
    int node = idx >> 5;
    int fp = idx & 31;                         // feat pair {2fp, 2fp+1}
    if (node >= n) return;
    f32x2v a = __builtin_nontemporal_load((const f32x2v*)(aggA + (size_t)node * HID + 2 * fp));
    float dn = dinv[node];
    float2 bv = *(const float2*)(b1 + 2 * fp);
    float g0 = dn * fmaxf(0.f, dn * a.x + bv.x);
    float g1 = dn * fmaxf(0.f, dn * a.y + bv.y);
    unsigned p = ((unsigned)f2bf(g1) << 16) | (unsigned)f2bf(g0);
    gcu[((size_t)(fp >> 3) * (n + 1) + node) * 8 + (fp & 7)] = p;
}

// ---------------- finish2: out = softmax( dinv*(aggB @ W2) + b2 ) ----------------
// Linearity: sum_src dinv_src*(h_src@W2) = (sum_src dinv_src*h_src)@W2.

__global__ __launch_bounds__(256) void finish2(const float* __restrict__ aggB,
                                               const float* __restrict__ dinv,
                                               const float* __restrict__ W2,
                                               const float* __restrict__ b2,
                                               float* __restrict__ out, int n) {
    __shared__ float2 w2p[32 * 40];   // [k/2][c]
    for (int i = threadIdx.x; i < 32 * 40; i += 256) {
        int k2 = i / 40, c = i - k2 * 40;
        w2p[i] = make_float2(W2[(2 * k2) * NCLS + c], W2[(2 * k2 + 1) * NCLS + c]);
    }
    __syncthreads();
    int wave = threadIdx.x >> 6, lane = threadIdx.x & 63;
    int node = blockIdx.x * 4 + wave;
    if (node >= n) return;
    int q = lane & 31;
    f32x2v hv = __builtin_nontemporal_load((const f32x2v*)(aggB + (size_t)node * HID + 2 * q));
    int c = (lane < 40) ? lane : 39;
    float o = 0.f;
    #pragma unroll
    for (int k = 0; k < 32; k++) {
        float sx = rl_f(hv.x, k);
        float sy = rl_f(hv.y, k);
        float2 wv = w2p[k * 40 + c];
        o += sx * wv.x + sy * wv.y;
    }
    float logit = dinv[node] * o + b2[c];
    float m = (lane < 40) ? logit : -INFINITY;
    #pragma unroll
    for (int off = 32; off; off >>= 1) m = fmaxf(m, __shfl_xor(m, off, 64));
    float ev = (lane < 40) ? expf(logit - m) : 0.0f;
    float ssum = ev;
    #pragma unroll
    for (int off = 32; off; off >>= 1) ssum += __shfl_xor(ssum, off, 64);
    if (lane < 40) out[(size_t)node * NCLS + lane] = ev / ssum;
}

// ---------------- launch ----------------

static inline size_t align256(size_t x) { return (x + 255) & ~(size_t)255; }

extern "C" void kernel_launch(void* const* d_in, const int* in_sizes, int n_in,
                              void* d_out, int out_size, void* d_ws, size_t ws_size,
                              hipStream_t stream) {
    const float* x  = (const float*)d_in[0];
    const int*   ei = (const int*)d_in[1];
    const float* W1 = (const float*)d_in[2];
    const float* b1 = (const float*)d_in[3];
    const float* W2 = (const float*)d_in[4];
    const float* b2 = (const float*)d_in[5];
    float* out = (float*)d_out;

    const int n = in_sizes[0] / NFEAT;      // 100000
    const int e = in_sizes[1] / 2;          // 3200000
    const int nbuckets = (n + BSIZE - 1) >> BSHIFT;   // 196

    char* ws = (char*)d_ws;
    size_t off = 0;
    int*   row_ptr  = (int*)(ws + off);   off += align256((size_t)(n + 1) * 4);
    float* dinv     = (float*)(ws + off); off += align256((size_t)n * 4);
    int*   bcursor  = (int*)(ws + off);   off += align256(256 * 4);
    int*   col      = (int*)(ws + off);   off += align256((size_t)e * 4);
    int*   stage    = (int*)(ws + off);   off += align256((size_t)nbuckets * BCAP * 4);
    unsigned short* w1bt = (unsigned short*)(ws + off); off += align256((size_t)HID * NFEAT * 2);
    unsigned short* t1c  = (unsigned short*)(ws + off); off += align256((size_t)4 * (n + 1) * 16 * 2);
    unsigned short* gc   = (unsigned short*)(ws + off); off += align256((size_t)4 * (n + 1) * 16 * 2);
    float* aggA = (float*)(ws + off);     off += align256((size_t)n * HID * 4);  // reused as aggB

    const int nsplit = ((n + 7) / 8) * 4;                    // node split point (mult of 4)
    const int ghalf  = (nsplit + 4 * NPW - 1) / (4 * NPW);   // groups per (chunk,half)
    const int aggblocks = ghalf * 8;

    (void)hipMemsetAsync(bcursor, 0, 256 * 4, stream);
    w1_to_bf16t<<<(HID * NFEAT) / 256, 256, 0, stream>>>(W1, w1bt, t1c, n);
    bin_scatter<<<(e + CHUNK - 1) / CHUNK, 256, 0, stream>>>(ei, e, nbuckets, bcursor, stage);
    bucket_csr<<<nbuckets, 256, 0, stream>>>(stage, bcursor, row_ptr, dinv, col, n, e, nbuckets);
    gemm1<<<(n + 63) / 64, 256, 0, stream>>>(x, w1bt, dinv, t1c, n);
    agg_pass<<<aggblocks, 256, 0, stream>>>(t1c, row_ptr, col, aggA, n, nsplit);
    finish1<<<(n + 7) / 8, 256, 0, stream>>>(aggA, dinv, b1, gc, n);
    agg_pass<<<aggblocks, 256, 0, stream>>>(gc, row_ptr, col, aggA, n, nsplit);
    finish2<<<(n + 3) / 4, 256, 0, stream>>>(aggA, dinv, W2, b2, out, n);
}

// Round 7
// 634.298 us; speedup vs baseline: 1.3946x; 1.1272x over previous
//
#include <hip/hip_runtime.h>
#include <hip/hip_bf16.h>
#include <math.h>

#define NFEAT 512
#define HID   64
#define NCLS  40
#define T2STRIDE 64             // t2 rows padded to 128B (one cache line)

#define BSHIFT 9
#define BSIZE  512              // nodes per bucket
#define BCAP   20480            // staged edges per bucket (avg ~16.3K, sd ~128)
#define CHUNK  4096             // edges per bin_scatter block

typedef __attribute__((ext_vector_type(8))) short bf16x8v;   // 8 bf16 = 4 VGPR
typedef __attribute__((ext_vector_type(4))) float f32x4v;    // MFMA acc
typedef __attribute__((ext_vector_type(4))) float v4f;

__device__ __forceinline__ float rl_f(float v, int l) {
    return __int_as_float(__builtin_amdgcn_readlane(__float_as_int(v), l));
}
__device__ __forceinline__ unsigned short f2bf(float f) {
    __hip_bfloat16 h = __float2bfloat16(f);
    return *(unsigned short*)&h;
}

// ---------------- prep: W1 -> bf16 transposed, zero cursors + sentinel rows ----------------
// (replaces 3 hipMemsetAsync dispatches + w1_to_bf16t)

__global__ __launch_bounds__(256) void prep(const float* __restrict__ W1,
                                            unsigned short* __restrict__ w1bt,
                                            int* __restrict__ bcursor,
                                            __hip_bfloat16* __restrict__ t1,
                                            __hip_bfloat16* __restrict__ t2, int n) {
    int idx = blockIdx.x * 256 + threadIdx.x;   // 64*512 = 32768
    int c = idx >> 9, k = idx & 511;
    w1bt[idx] = f2bf(W1[k * HID + c]);
    if (blockIdx.x == 0) bcursor[threadIdx.x] = 0;
    if (blockIdx.x == 1 && threadIdx.x < 32)
        ((unsigned*)(t1 + (size_t)n * HID))[threadIdx.x] = 0;       // t1 sentinel row
    if (blockIdx.x == 2 && threadIdx.x < 32)
        ((unsigned*)(t2 + (size_t)n * T2STRIDE))[threadIdx.x] = 0;  // t2 sentinel row
}

// ---------------- CSR build: two-level binning, 512 threads (2x TLP vs R3) ----------------

__global__ __launch_bounds__(512) void bin_scatter(const int* __restrict__ ei, int e,
                                                   int nbuckets,
                                                   int* __restrict__ bucket_cursor,
                                                   int* __restrict__ stage) {
    __shared__ int packed_s[CHUNK];
    __shared__ unsigned char bkt_s[CHUNK];
    __shared__ int hist[256];
    __shared__ int base_s[256];
    __shared__ int lcur[256];
    int t = threadIdx.x;
    int b0 = blockIdx.x * CHUNK;
    int cnt = min(CHUNK, e - b0);
    if (t < 256) hist[t] = 0;
    __syncthreads();
    for (int i = t; i < cnt; i += 512) {
        int s = __builtin_nontemporal_load(ei + b0 + i);
        int d = __builtin_nontemporal_load(ei + e + b0 + i);
        packed_s[i] = (s << BSHIFT) | (d & (BSIZE - 1));
        bkt_s[i] = (unsigned char)(d >> BSHIFT);
        atomicAdd(&hist[d >> BSHIFT], 1);
    }
    __syncthreads();
    if (t < 256) {
        int c = (t < nbuckets) ? hist[t] : 0;
        base_s[t] = c ? atomicAdd(&bucket_cursor[t], c) : 0;
        lcur[t] = 0;
    }
    __syncthreads();
    for (int i = t; i < cnt; i += 512) {
        int bk = bkt_s[i];
        int pos = base_s[bk] + atomicAdd(&lcur[bk], 1);
        if (pos < BCAP) __builtin_nontemporal_store(packed_s[i], stage + (size_t)bk * BCAP + pos);
    }
}

// bucket_csr: 512 threads (R3 ran 196 blocks x 256 thr = <=1 block/CU, zero TLP,
// all LDS-atomic latency exposed; 512 thr halves per-thread serial atomic chains).
// Bucket-base scan folded in (redundant per-block scan of the 196 cursors).

__global__ __launch_bounds__(512) void bucket_csr(const int* __restrict__ stage,
                                                  const int* __restrict__ bucket_cursor,
                                                  int* __restrict__ row_ptr,
                                                  float* __restrict__ dinv,
                                                  int* __restrict__ col,
                                                  int n, int e, int nbuckets) {
    __shared__ int sc[256];
    __shared__ int hist[BSIZE];    // 512
    __shared__ int lbase[BSIZE];
    __shared__ int psum[BSIZE];
    int b = blockIdx.x;
    int t = threadIdx.x;
    // scan of bucket_cursor (<=256 entries) by first 256 threads
    if (t < 256) sc[t] = (t < nbuckets) ? bucket_cursor[t] : 0;
    __syncthreads();
    #pragma unroll
    for (int off = 1; off < 256; off <<= 1) {
        int u = (t < 256 && t >= off) ? sc[t - off] : 0;
        __syncthreads();
        if (t < 256) sc[t] += u;
        __syncthreads();
    }
    int base0 = (b > 0) ? sc[b - 1] : 0;
    if (b == 0 && t == 0) row_ptr[n] = e;

    int cnt = min(bucket_cursor[b], BCAP);
    int node0 = b << BSHIFT;
    int nnodes = min(BSIZE, n - node0);
    const int* st = stage + (size_t)b * BCAP;
    hist[t] = 0;                   // 512 threads, 512 entries: 1:1
    __syncthreads();
    for (int i = t; i < cnt; i += 512)
        atomicAdd(&hist[__builtin_nontemporal_load(st + i) & (BSIZE - 1)], 1);
    __syncthreads();
    int d = hist[t];
    psum[t] = d;
    __syncthreads();
    #pragma unroll
    for (int off = 1; off < 512; off <<= 1) {
        int u = (t >= off) ? psum[t - off] : 0;
        __syncthreads();
        psum[t] += u;
        __syncthreads();
    }
    int myl = psum[t] - d;         // exclusive prefix, kept in register
    lbase[t] = myl;
    if (t < nnodes) {
        row_ptr[node0 + t] = base0 + myl;
        dinv[node0 + t] = rsqrtf((float)(d + 1));
    }
    __syncthreads();               // all lbase visible before atomics mutate it
    for (int i = t; i < cnt; i += 512) {
        int p = __builtin_nontemporal_load(st + i);
        int pos = atomicAdd(&lbase[p & (BSIZE - 1)], 1);
        col[base0 + pos] = ((unsigned)p) >> BSHIFT;
    }
}

// ---------------- GEMM1 (MFMA): t1 = bf16( dinv[:,None] * (x @ W1) ) ----------------
// Fragment layout (m89/m91-verified): A row=lane&15, k=8*(lane>>4)+j;
// B col=lane&15, same k; C/D col=lane&15, row=4*(lane>>4)+reg.

__global__ __launch_bounds__(256) void gemm1(const float* __restrict__ x,
                                             const unsigned short* __restrict__ w1bt,
                                             const float* __restrict__ dinv,
                                             __hip_bfloat16* __restrict__ t1, int n) {
    __shared__ __align__(16) unsigned short As[64][40];  // [row][k], pad 40
    __shared__ __align__(16) unsigned short Bs[64][40];  // [col][k], pad 40
    int t = threadIdx.x;
    int m0 = blockIdx.x * 64;
    int w = t >> 6, lane = t & 63;
    int lrow = lane & 15, lkg = lane >> 4;
    f32x4v acc[4] = {};

    int arow = t >> 2;        // staging row / col (0..63)
    int akg = t & 3;          // k-group of 8
    int grow = m0 + arow; if (grow >= n) grow = n - 1;
    const float* xrow = x + (size_t)grow * NFEAT;

    for (int k0 = 0; k0 < NFEAT; k0 += 32) {
        v4f v0 = __builtin_nontemporal_load((const v4f*)(xrow + k0 + akg * 8));
        v4f v1 = __builtin_nontemporal_load((const v4f*)(xrow + k0 + akg * 8 + 4));
        union { unsigned short u[8]; uint4 q; } P;
        P.u[0] = f2bf(v0.x); P.u[1] = f2bf(v0.y); P.u[2] = f2bf(v0.z); P.u[3] = f2bf(v0.w);
        P.u[4] = f2bf(v1.x); P.u[5] = f2bf(v1.y); P.u[6] = f2bf(v1.z); P.u[7] = f2bf(v1.w);
        *(uint4*)&As[arow][akg * 8] = P.q;
        *(uint4*)&Bs[arow][akg * 8] = *(const uint4*)(w1bt + arow * 512 + k0 + akg * 8);
        __syncthreads();
        bf16x8v af = *(const bf16x8v*)&As[w * 16 + lrow][lkg * 8];
        #pragma unroll
        for (int nb = 0; nb < 4; nb++) {
            bf16x8v bfv = *(const bf16x8v*)&Bs[nb * 16 + lrow][lkg * 8];
            acc[nb] = __builtin_amdgcn_mfma_f32_16x16x32_bf16(af, bfv, acc[nb], 0, 0, 0);
        }
        __syncthreads();
    }
    #pragma unroll
    for (int r = 0; r < 4; r++) {
        int row = m0 + w * 16 + lkg * 4 + r;
        if (row < n) {
            float d = dinv[row];
            #pragma unroll
            for (int nb = 0; nb < 4; nb++) {
                t1[(size_t)row * HID + nb * 16 + lrow] = __float2bfloat16(acc[nb][r] * d);
            }
        }
    }
}

// ---------------- fused agg1 + gemm2 (R3-proven structure) ----------------
// 8 lanes per 128B row (dwordx4/lane) -> 8 edges per VMEM instruction, depth-4
// (32 edges, 4KB in flight/wave). ds_bpermute index broadcast; zero sentinel row t1[n].
// col read nontemporally (protect hot t1 in L2/L3). GEMM2 via v_readlane + LDS float2.

#define UNPACK_ADD(pv) do { \
    acc[0] += __uint_as_float((pv).x << 16); acc[1] += __uint_as_float((pv).x & 0xffff0000u); \
    acc[2] += __uint_as_float((pv).y << 16); acc[3] += __uint_as_float((pv).y & 0xffff0000u); \
    acc[4] += __uint_as_float((pv).z << 16); acc[5] += __uint_as_float((pv).z & 0xffff0000u); \
    acc[6] += __uint_as_float((pv).w << 16); acc[7] += __uint_as_float((pv).w & 0xffff0000u); } while (0)

__global__ __launch_bounds__(256) void agg1_gemm2(const __hip_bfloat16* __restrict__ t1,
                                                  const int* __restrict__ row_ptr,
                                                  const int* __restrict__ col,
                                                  const float* __restrict__ dinv,
                                                  const float* __restrict__ b1,
                                                  const float* __restrict__ W2,
                                                  __hip_bfloat16* __restrict__ t2, int n) {
    __shared__ float2 w2p[32 * 40];   // [k/2][c] float2 = {W2[2k'][c], W2[2k'+1][c]}
    for (int i = threadIdx.x; i < 32 * 40; i += 256) {
        int k2 = i / 40, c = i - k2 * 40;
        w2p[i] = make_float2(W2[(2 * k2) * 40 + c], W2[(2 * k2 + 1) * 40 + c]);
    }
    __syncthreads();

    int wave = threadIdx.x >> 6;
    int lane = threadIdx.x & 63;
    int node0 = blockIdx.x * 4 + wave;
    int node = (node0 < n) ? node0 : n - 1;   // clamp; store masked at end
    int r = lane & 7;                          // 16B chunk within row (feats 8r..8r+7)
    int slot = lane >> 3;                      // edge slot within 8-edge group

    const uint4* t1q = (const uint4*)t1;       // row = 8 uint4
    int s0 = row_ptr[node], s1 = row_ptr[node + 1];

    float acc[8] = {0.f, 0.f, 0.f, 0.f, 0.f, 0.f, 0.f, 0.f};

    // self loop: slot 0 only (r == lane for lane < 8)
    if (lane < 8) {
        uint4 pv = t1q[(size_t)node * 8 + lane];
        UNPACK_ADD(pv);
    }

    int bpbase = slot * 4;                     // bpermute byte index base
    for (int jb = s0; jb < s1; jb += 32) {
        int rem = s1 - jb;
        int ll = lane & 31;
        int cidx = __builtin_nontemporal_load(col + jb + ((ll < rem) ? ll : 0));
        int srcg[4];
        #pragma unroll
        for (int g = 0; g < 4; g++) {
            int src = __builtin_amdgcn_ds_bpermute(bpbase + 32 * g, cidx);
            srcg[g] = (8 * g + slot < rem) ? src : n;   // sentinel -> zero row
        }
        uint4 pv[4];
        #pragma unroll
        for (int g = 0; g < 4; g++) pv[g] = t1q[(size_t)srcg[g] * 8 + r];
        #pragma unroll
        for (int g = 0; g < 4; g++) { UNPACK_ADD(pv[g]); }
    }

    // cross-slot butterfly: every lane ends with full sums for feats 8r..8r+7
    #pragma unroll
    for (int off = 8; off < 64; off <<= 1) {
        #pragma unroll
        for (int j = 0; j < 8; j++) acc[j] += __shfl_xor(acc[j], off, 64);
    }

    float dn = dinv[node];
    const float4* b1q = (const float4*)b1;
    float4 ba = b1q[2 * r];
    float4 bb = b1q[2 * r + 1];
    float hv[8];
    hv[0] = fmaxf(0.f, dn * acc[0] + ba.x);
    hv[1] = fmaxf(0.f, dn * acc[1] + ba.y);
    hv[2] = fmaxf(0.f, dn * acc[2] + ba.z);
    hv[3] = fmaxf(0.f, dn * acc[3] + ba.w);
    hv[4] = fmaxf(0.f, dn * acc[4] + bb.x);
    hv[5] = fmaxf(0.f, dn * acc[5] + bb.y);
    hv[6] = fmaxf(0.f, dn * acc[6] + bb.z);
    hv[7] = fmaxf(0.f, dn * acc[7] + bb.w);

    int c = (lane < 40) ? lane : 39;
    float o = 0.0f;
    #pragma unroll
    for (int rr = 0; rr < 8; rr++) {
        #pragma unroll
        for (int j2 = 0; j2 < 4; j2++) {
            float ha = rl_f(hv[2 * j2],     rr);   // h[8rr + 2j2]
            float hb = rl_f(hv[2 * j2 + 1], rr);   // h[8rr + 2j2+1]
            float2 wv = w2p[(4 * rr + j2) * 40 + c];
            o += ha * wv.x + hb * wv.y;
        }
    }
    if (node0 < n && lane < 40)
        t2[(size_t)node * T2STRIDE + lane] = __float2bfloat16(dn * o);
}

// ---------------- agg2 + bias + softmax (R3-proven) ----------------
// t2 rows padded to 128B: each random gather touches exactly 1 cache line.

__global__ __launch_bounds__(256) void agg2_softmax(const __hip_bfloat16* __restrict__ t2,
                                                    const int* __restrict__ row_ptr,
                                                    const int* __restrict__ col,
                                                    const float* __restrict__ dinv,
                                                    const float* __restrict__ b2,
                                                    float* __restrict__ out, int n) {
    int wave = threadIdx.x >> 6;
    int lane = threadIdx.x & 63;
    int node = blockIdx.x * 4 + wave;
    if (node >= n) return;
    int h = lane >> 5;                 // which edge of the pair
    int p = lane & 31;                 // class-pair index
    int pc = (p < 20) ? p : 19;        // clamped (lanes 20-31 dead weight)
    const unsigned* t2d = (const unsigned*)t2;   // padded row = 32 dwords
    int s0 = row_ptr[node], s1 = row_ptr[node + 1];

    float ax = 0.f, ay = 0.f;
    if (h == 0) {                      // self loop counted once
        unsigned v = t2d[(size_t)node * 32 + pc];
        ax = __uint_as_float(v << 16);
        ay = __uint_as_float(v & 0xffff0000u);
    }
    for (int jb = s0; jb < s1; jb += 16) {
        int rem = s1 - jb;
        int cv = __builtin_nontemporal_load(col + jb + ((lane < rem) ? lane : 0));
        int srcg[8];
        #pragma unroll
        for (int i = 0; i < 8; i++) {
            int eid = 2 * i + h;
            int src = __builtin_amdgcn_ds_bpermute(4 * eid, cv);
            srcg[i] = (eid < rem) ? src : n;           // sentinel -> zero row
        }
        unsigned pv[8];
        #pragma unroll
        for (int i = 0; i < 8; i++) pv[i] = t2d[(size_t)srcg[i] * 32 + pc];
        #pragma unroll
        for (int i = 0; i < 8; i++) {
            ax += __uint_as_float(pv[i] << 16);
            ay += __uint_as_float(pv[i] & 0xffff0000u);
        }
    }
    ax += __shfl_xor(ax, 32, 64);
    ay += __shfl_xor(ay, 32, 64);

    float dn = dinv[node];
    float2 bv = *(const float2*)(b2 + 2 * pc);
    float lx = dn * ax + bv.x;
    float ly = dn * ay + bv.y;
    float m = (p < 20) ? fmaxf(lx, ly) : -INFINITY;
    #pragma unroll
    for (int off = 16; off; off >>= 1) m = fmaxf(m, __shfl_xor(m, off, 64));
    float ex = (p < 20) ? expf(lx - m) : 0.0f;
    float ey = (p < 20) ? expf(ly - m) : 0.0f;
    float ssum = ex + ey;
    #pragma unroll
    for (int off = 16; off; off >>= 1) ssum += __shfl_xor(ssum, off, 64);
    if (h == 0 && p < 20) {
        *(float2*)(out + (size_t)node * NCLS + 2 * p) = make_float2(ex / ssum, ey / ssum);
    }
}

// ---------------- launch ----------------

static inline size_t align256(size_t x) { return (x + 255) & ~(size_t)255; }

extern "C" void kernel_launch(void* const* d_in, const int* in_sizes, int n_in,
                              void* d_out, int out_size, void* d_ws, size_t ws_size,
                              hipStream_t stream) {
    const float* x  = (const float*)d_in[0];
    const int*   ei = (const int*)d_in[1];
    const float* W1 = (const float*)d_in[2];
    const float* b1 = (const float*)d_in[3];
    const float* W2 = (const float*)d_in[4];
    const float* b2 = (const float*)d_in[5];
    float* out = (float*)d_out;

    const int n = in_sizes[0] / NFEAT;      // 100000
    const int e = in_sizes[1] / 2;          // 3200000
    const int nbuckets = (n + BSIZE - 1) >> BSHIFT;   // 196

    char* ws = (char*)d_ws;
    size_t off = 0;
    int*   row_ptr  = (int*)(ws + off);   off += align256((size_t)(n + 1) * 4);
    float* dinv     = (float*)(ws + off); off += align256((size_t)n * 4);
    int*   bcursor  = (int*)(ws + off);   off += align256(256 * 4);
    int*   col      = (int*)(ws + off);   off += align256((size_t)e * 4);
    int*   stage    = (int*)(ws + off);   off += align256((size_t)nbuckets * BCAP * 4);
    unsigned short* w1bt = (unsigned short*)(ws + off); off += align256((size_t)HID * NFEAT * 2);
    __hip_bfloat16* t1 = (__hip_bfloat16*)(ws + off); off += align256((size_t)(n + 1) * HID * 2);
    __hip_bfloat16* t2 = (__hip_bfloat16*)(ws + off); off += align256((size_t)(n + 1) * T2STRIDE * 2);

    prep<<<(HID * NFEAT) / 256, 256, 0, stream>>>(W1, w1bt, bcursor, t1, t2, n);
    bin_scatter<<<(e + CHUNK - 1) / CHUNK, 512, 0, stream>>>(ei, e, nbuckets, bcursor, stage);
    bucket_csr<<<nbuckets, 512, 0, stream>>>(stage, bcursor, row_ptr, dinv, col, n, e, nbuckets);
    gemm1<<<(n + 63) / 64, 256, 0, stream>>>(x, w1bt, dinv, t1, n);
    agg1_gemm2<<<(n + 3) / 4, 256, 0, stream>>>(t1, row_ptr, col, dinv, b1, W2, t2, n);
    agg2_softmax<<<(n + 3) / 4, 256, 0, stream>>>(t2, row_ptr, col, dinv, b2, out, n);
}

// Round 8
// 557.171 us; speedup vs baseline: 1.5877x; 1.1384x over previous
//
#include <hip/hip_runtime.h>
#include <hip/hip_bf16.h>
#include <math.h>

#define NFEAT 512
#define HID   64
#define NCLS  40
#define T2STRIDE 64             // t2 rows padded to 128B (one cache line)

#define BSHIFT 9
#define BSIZE  512              // nodes per bucket
#define BCAP   20480            // staged edges per bucket (avg ~16.3K, sd ~128)
#define CHUNK  4096             // edges per bin_scatter block

typedef __attribute__((ext_vector_type(8))) short bf16x8v;   // 8 bf16 = 4 VGPR
typedef __attribute__((ext_vector_type(4))) float f32x4v;    // MFMA acc
typedef __attribute__((ext_vector_type(4))) float v4f;

__device__ __forceinline__ float rl_f(float v, int l) {
    return __int_as_float(__builtin_amdgcn_readlane(__float_as_int(v), l));
}
__device__ __forceinline__ unsigned short f2bf(float f) {
    __hip_bfloat16 h = __float2bfloat16(f);
    return *(unsigned short*)&h;
}

// ---------------- CSR build: two-level binning (R3-exact; do not touch without timing) ----------------

__global__ __launch_bounds__(256) void bin_scatter(const int* __restrict__ ei, int e,
                                                   int nbuckets,
                                                   int* __restrict__ bucket_cursor,
                                                   int* __restrict__ stage) {
    __shared__ int packed_s[CHUNK];
    __shared__ unsigned char bkt_s[CHUNK];
    __shared__ int hist[256];
    __shared__ int base_s[256];
    __shared__ int lcur[256];
    int t = threadIdx.x;
    int b0 = blockIdx.x * CHUNK;
    int cnt = min(CHUNK, e - b0);
    for (int i = t; i < 256; i += 256) hist[i] = 0;
    __syncthreads();
    for (int i = t; i < cnt; i += 256) {
        int s = ei[b0 + i];
        int d = ei[e + b0 + i];
        packed_s[i] = (s << BSHIFT) | (d & (BSIZE - 1));
        bkt_s[i] = (unsigned char)(d >> BSHIFT);
        atomicAdd(&hist[d >> BSHIFT], 1);
    }
    __syncthreads();
    for (int i = t; i < nbuckets; i += 256) {
        int c = hist[i];
        base_s[i] = c ? atomicAdd(&bucket_cursor[i], c) : 0;
        lcur[i] = 0;
    }
    __syncthreads();
    for (int i = t; i < cnt; i += 256) {
        int bk = bkt_s[i];
        int pos = base_s[bk] + atomicAdd(&lcur[bk], 1);
        if (pos < BCAP) stage[(size_t)bk * BCAP + pos] = packed_s[i];
    }
}

// bucket_csr with the bucket-base scan folded in (R3-exact)
__global__ __launch_bounds__(256) void bucket_csr(const int* __restrict__ stage,
                                                  const int* __restrict__ bucket_cursor,
                                                  int* __restrict__ row_ptr,
                                                  float* __restrict__ dinv,
                                                  int* __restrict__ col,
                                                  int n, int e, int nbuckets) {
    __shared__ int sc[256];
    __shared__ int hist[BSIZE];
    __shared__ int lbase[BSIZE];
    __shared__ int psum[256];
    int b = blockIdx.x;
    int t = threadIdx.x;
    int v = (t < nbuckets) ? bucket_cursor[t] : 0;
    sc[t] = v;
    __syncthreads();
    #pragma unroll
    for (int off = 1; off < 256; off <<= 1) {
        int u = (t >= off) ? sc[t - off] : 0;
        __syncthreads();
        sc[t] += u;
        __syncthreads();
    }
    int base0 = (b > 0) ? sc[b - 1] : 0;
    if (b == 0 && t == 0) row_ptr[n] = e;

    int cnt = min(bucket_cursor[b], BCAP);
    int node0 = b << BSHIFT;
    int nnodes = min(BSIZE, n - node0);
    const int* st = stage + (size_t)b * BCAP;
    for (int i = t; i < BSIZE; i += 256) hist[i] = 0;
    __syncthreads();
    for (int i = t; i < cnt; i += 256) atomicAdd(&hist[st[i] & (BSIZE - 1)], 1);
    __syncthreads();
    int h0 = hist[2 * t], h1 = hist[2 * t + 1];
    int pair = h0 + h1;
    psum[t] = pair;
    __syncthreads();
    #pragma unroll
    for (int off = 1; off < 256; off <<= 1) {
        int u = (t >= off) ? psum[t - off] : 0;
        __syncthreads();
        psum[t] += u;
        __syncthreads();
    }
    int ex = psum[t] - pair;
    lbase[2 * t] = ex;
    lbase[2 * t + 1] = ex + h0;
    __syncthreads();
    for (int i = t; i < nnodes; i += 256) {
        row_ptr[node0 + i] = base0 + lbase[i];
        dinv[node0 + i] = rsqrtf((float)(hist[i] + 1));
    }
    __syncthreads();
    for (int i = t; i < cnt; i += 256) {
        int p = st[i];
        int pos = atomicAdd(&lbase[p & (BSIZE - 1)], 1);
        col[base0 + pos] = ((unsigned)p) >> BSHIFT;
    }
}

// ---------------- one-time: W1 -> bf16, transposed [64][512] ----------------

__global__ __launch_bounds__(256) void w1_to_bf16t(const float* __restrict__ W1,
                                                   unsigned short* __restrict__ w1bt) {
    int idx = blockIdx.x * 256 + threadIdx.x;   // 64*512 = 32768
    int c = idx >> 9, k = idx & 511;
    w1bt[idx] = f2bf(W1[k * HID + c]);
}

// ---------------- GEMM1 (MFMA): t1 = bf16( dinv[:,None] * (x @ W1) ) ----------------
// x read nontemporally (205MB one-shot stream; protects freshly-written t1 in cache).

__global__ __launch_bounds__(256) void gemm1(const float* __restrict__ x,
                                             const unsigned short* __restrict__ w1bt,
                                             const float* __restrict__ dinv,
                                             __hip_bfloat16* __restrict__ t1, int n) {
    __shared__ __align__(16) unsigned short As[64][40];  // [row][k], pad 40
    __shared__ __align__(16) unsigned short Bs[64][40];  // [col][k], pad 40
    int t = threadIdx.x;
    int m0 = blockIdx.x * 64;
    int w = t >> 6, lane = t & 63;
    int lrow = lane & 15, lkg = lane >> 4;
    f32x4v acc[4] = {};

    int arow = t >> 2;        // staging row / col (0..63)
    int akg = t & 3;          // k-group of 8
    int grow = m0 + arow; if (grow >= n) grow = n - 1;
    const float* xrow = x + (size_t)grow * NFEAT;

    for (int k0 = 0; k0 < NFEAT; k0 += 32) {
        v4f v0 = __builtin_nontemporal_load((const v4f*)(xrow + k0 + akg * 8));
        v4f v1 = __builtin_nontemporal_load((const v4f*)(xrow + k0 + akg * 8 + 4));
        union { unsigned short u[8]; uint4 q; } P;
        P.u[0] = f2bf(v0.x); P.u[1] = f2bf(v0.y); P.u[2] = f2bf(v0.z); P.u[3] = f2bf(v0.w);
        P.u[4] = f2bf(v1.x); P.u[5] = f2bf(v1.y); P.u[6] = f2bf(v1.z); P.u[7] = f2bf(v1.w);
        *(uint4*)&As[arow][akg * 8] = P.q;
        *(uint4*)&Bs[arow][akg * 8] = *(const uint4*)(w1bt + arow * 512 + k0 + akg * 8);
        __syncthreads();
        bf16x8v af = *(const bf16x8v*)&As[w * 16 + lrow][lkg * 8];
        #pragma unroll
        for (int nb = 0; nb < 4; nb++) {
            bf16x8v bfv = *(const bf16x8v*)&Bs[nb * 16 + lrow][lkg * 8];
            acc[nb] = __builtin_amdgcn_mfma_f32_16x16x32_bf16(af, bfv, acc[nb], 0, 0, 0);
        }
        __syncthreads();
    }
    #pragma unroll
    for (int r = 0; r < 4; r++) {
        int row = m0 + w * 16 + lkg * 4 + r;
        if (row < n) {
            float d = dinv[row];
            #pragma unroll
            for (int nb = 0; nb < 4; nb++) {
                t1[(size_t)row * HID + nb * 16 + lrow] = __float2bfloat16(acc[nb][r] * d);
            }
        }
    }
}

// ---------------- fused agg1 + gemm2 ----------------
// Full 32-edge batches carry NO sentinel machinery (no rem compares / cndmask);
// tail handled by static 2-group 16-edge sub-batches (2 loads in flight kept).
// col nontemporal (one-shot stream; protects hot 12.8MB t1 table in L2/L3).

#define UNPACK_ADD(pv) do { \
    acc[0] += __uint_as_float((pv).x << 16); acc[1] += __uint_as_float((pv).x & 0xffff0000u); \
    acc[2] += __uint_as_float((pv).y << 16); acc[3] += __uint_as_float((pv).y & 0xffff0000u); \
    acc[4] += __uint_as_float((pv).z << 16); acc[5] += __uint_as_float((pv).z & 0xffff0000u); \
    acc[6] += __uint_as_float((pv).w << 16); acc[7] += __uint_as_float((pv).w & 0xffff0000u); } while (0)

__global__ __launch_bounds__(256) void agg1_gemm2(const __hip_bfloat16* __restrict__ t1,
                                                  const int* __restrict__ row_ptr,
                                                  const int* __restrict__ col,
                                                  const float* __restrict__ dinv,
                                                  const float* __restrict__ b1,
                                                  const float* __restrict__ W2,
                                                  __hip_bfloat16* __restrict__ t2, int n) {
    __shared__ float2 w2p[32 * 40];   // [k/2][c] float2 = {W2[2k'][c], W2[2k'+1][c]}
    for (int i = threadIdx.x; i < 32 * 40; i += 256) {
        int k2 = i / 40, c = i - k2 * 40;
        w2p[i] = make_float2(W2[(2 * k2) * 40 + c], W2[(2 * k2 + 1) * 40 + c]);
    }
    __syncthreads();

    int wave = threadIdx.x >> 6;
    int lane = threadIdx.x & 63;
    int node0 = blockIdx.x * 4 + wave;
    int node = (node0 < n) ? node0 : n - 1;   // clamp; store masked at end
    int r = lane & 7;                          // 16B chunk within row (feats 8r..8r+7)
    int slot = lane >> 3;                      // edge slot within 8-edge group

    const uint4* t1q = (const uint4*)t1;       // row = 8 uint4
    int s0 = row_ptr[node], s1 = row_ptr[node + 1];

    float acc[8] = {0.f, 0.f, 0.f, 0.f, 0.f, 0.f, 0.f, 0.f};

    // self loop: slot 0 only (r == lane for lane < 8)
    if (lane < 8) {
        uint4 pv = t1q[(size_t)node * 8 + lane];
        UNPACK_ADD(pv);
    }

    int bpbase = slot * 4;                     // bpermute byte index base
    int jb = s0;
    // full batches: 32 edges, 4 dwordx4 gathers in flight, zero predication
    for (; jb + 32 <= s1; jb += 32) {
        int cidx = __builtin_nontemporal_load(col + jb + (lane & 31));
        int srcg[4];
        #pragma unroll
        for (int g = 0; g < 4; g++)
            srcg[g] = __builtin_amdgcn_ds_bpermute(bpbase + 32 * g, cidx);
        uint4 pv[4];
        #pragma unroll
        for (int g = 0; g < 4; g++) pv[g] = t1q[(size_t)srcg[g] * 8 + r];
        #pragma unroll
        for (int g = 0; g < 4; g++) { UNPACK_ADD(pv[g]); }
    }
    // tail: static 2-group (16-edge) sub-batches, sentinel-predicated
    for (; jb < s1; jb += 16) {
        int rem = s1 - jb;                     // 1..31 first pass, 1..15 second
        int ll = lane & 15;
        int cidx = __builtin_nontemporal_load(col + jb + ((ll < rem) ? ll : 0));
        #pragma unroll
        for (int g = 0; g < 2; g++) {
            int src = __builtin_amdgcn_ds_bpermute(bpbase + 32 * g, cidx);
            src = (8 * g + slot < rem) ? src : n;   // sentinel -> zero row
            uint4 pv = t1q[(size_t)src * 8 + r];
            UNPACK_ADD(pv);
        }
    }

    // cross-slot butterfly: every lane ends with full sums for feats 8r..8r+7
    #pragma unroll
    for (int off = 8; off < 64; off <<= 1) {
        #pragma unroll
        for (int j = 0; j < 8; j++) acc[j] += __shfl_xor(acc[j], off, 64);
    }

    float dn = dinv[node];
    const float4* b1q = (const float4*)b1;
    float4 ba = b1q[2 * r];
    float4 bb = b1q[2 * r + 1];
    float hv[8];
    hv[0] = fmaxf(0.f, dn * acc[0] + ba.x);
    hv[1] = fmaxf(0.f, dn * acc[1] + ba.y);
    hv[2] = fmaxf(0.f, dn * acc[2] + ba.z);
    hv[3] = fmaxf(0.f, dn * acc[3] + ba.w);
    hv[4] = fmaxf(0.f, dn * acc[4] + bb.x);
    hv[5] = fmaxf(0.f, dn * acc[5] + bb.y);
    hv[6] = fmaxf(0.f, dn * acc[6] + bb.z);
    hv[7] = fmaxf(0.f, dn * acc[7] + bb.w);

    int c = (lane < 40) ? lane : 39;
    float o = 0.0f;
    #pragma unroll
    for (int rr = 0; rr < 8; rr++) {
        #pragma unroll
        for (int j2 = 0; j2 < 4; j2++) {
            float ha = rl_f(hv[2 * j2],     rr);   // h[8rr + 2j2]
            float hb = rl_f(hv[2 * j2 + 1], rr);   // h[8rr + 2j2+1]
            float2 wv = w2p[(4 * rr + j2) * 40 + c];
            o += ha * wv.x + hb * wv.y;
        }
    }
    if (node0 < n && lane < 40)
        t2[(size_t)node * T2STRIDE + lane] = __float2bfloat16(dn * o);
}

// ---------------- agg2 + bias + softmax ----------------
// Full 16-edge batches unpredicated; 8-edge static-4-load tail. col nontemporal.

__global__ __launch_bounds__(256) void agg2_softmax(const __hip_bfloat16* __restrict__ t2,
                                                    const int* __restrict__ row_ptr,
                                                    const int* __restrict__ col,
                                                    const float* __restrict__ dinv,
                                                    const float* __restrict__ b2,
                                                    float* __restrict__ out, int n) {
    int wave = threadIdx.x >> 6;
    int lane = threadIdx.x & 63;
    int node = blockIdx.x * 4 + wave;
    if (node >= n) return;
    int h = lane >> 5;                 // which edge of the pair
    int p = lane & 31;                 // class-pair index
    int pc = (p < 20) ? p : 19;        // clamped (lanes 20-31 dead weight)
    const unsigned* t2d = (const unsigned*)t2;   // padded row = 32 dwords
    int s0 = row_ptr[node], s1 = row_ptr[node + 1];

    float ax = 0.f, ay = 0.f;
    if (h == 0) {                      // self loop counted once
        unsigned v = t2d[(size_t)node * 32 + pc];
        ax = __uint_as_float(v << 16);
        ay = __uint_as_float(v & 0xffff0000u);
    }
    int jb = s0;
    // full batches: 16 edges, 8 dword gathers in flight, zero predication
    for (; jb + 16 <= s1; jb += 16) {
        int cv = __builtin_nontemporal_load(col + jb + (lane & 15));
        int srcg[8];
        #pragma unroll
        for (int i = 0; i < 8; i++)
            srcg[i] = __builtin_amdgcn_ds_bpermute(4 * (2 * i + h), cv);
        unsigned pv[8];
        #pragma unroll
        for (int i = 0; i < 8; i++) pv[i] = t2d[(size_t)srcg[i] * 32 + pc];
        #pragma unroll
        for (int i = 0; i < 8; i++) {
            ax += __uint_as_float(pv[i] << 16);
            ay += __uint_as_float(pv[i] & 0xffff0000u);
        }
    }
    // tail: 8-edge sub-batches (4 loads), sentinel-predicated
    for (; jb < s1; jb += 8) {
        int rem = s1 - jb;             // 1..15 first pass, 1..7 second
        int ll = lane & 7;
        int cv = __builtin_nontemporal_load(col + jb + ((ll < rem) ? ll : 0));
        #pragma unroll
        for (int i = 0; i < 4; i++) {
            int eid = 2 * i + h;
            int src = __builtin_amdgcn_ds_bpermute(4 * eid, cv);
            src = (eid < rem) ? src : n;           // sentinel -> zero row
            unsigned pv = t2d[(size_t)src * 32 + pc];
            ax += __uint_as_float(pv << 16);
            ay += __uint_as_float(pv & 0xffff0000u);
        }
    }
    ax += __shfl_xor(ax, 32, 64);
    ay += __shfl_xor(ay, 32, 64);

    float dn = dinv[node];
    float2 bv = *(const float2*)(b2 + 2 * pc);
    float lx = dn * ax + bv.x;
    float ly = dn * ay + bv.y;
    float m = (p < 20) ? fmaxf(lx, ly) : -INFINITY;
    #pragma unroll
    for (int off = 16; off; off >>= 1) m = fmaxf(m, __shfl_xor(m, off, 64));
    float ex = (p < 20) ? expf(lx - m) : 0.0f;
    float ey = (p < 20) ? expf(ly - m) : 0.0f;
    float ssum = ex + ey;
    #pragma unroll
    for (int off = 16; off; off >>= 1) ssum += __shfl_xor(ssum, off, 64);
    if (h == 0 && p < 20) {
        *(float2*)(out + (size_t)node * NCLS + 2 * p) = make_float2(ex / ssum, ey / ssum);
    }
}

// ---------------- launch ----------------

static inline size_t align256(size_t x) { return (x + 255) & ~(size_t)255; }

extern "C" void kernel_launch(void* const* d_in, const int* in_sizes, int n_in,
                              void* d_out, int out_size, void* d_ws, size_t ws_size,
                              hipStream_t stream) {
    const float* x  = (const float*)d_in[0];
    const int*   ei = (const int*)d_in[1];
    const float* W1 = (const float*)d_in[2];
    const float* b1 = (const float*)d_in[3];
    const float* W2 = (const float*)d_in[4];
    const float* b2 = (const float*)d_in[5];
    float* out = (float*)d_out;

    const int n = in_sizes[0] / NFEAT;      // 100000
    const int e = in_sizes[1] / 2;          // 3200000
    const int nbuckets = (n + BSIZE - 1) >> BSHIFT;   // 196

    char* ws = (char*)d_ws;
    size_t off = 0;
    int*   row_ptr  = (int*)(ws + off);   off += align256((size_t)(n + 1) * 4);
    float* dinv     = (float*)(ws + off); off += align256((size_t)n * 4);
    int*   bcursor  = (int*)(ws + off);   off += align256(256 * 4);
    int*   col      = (int*)(ws + off);   off += align256((size_t)e * 4);
    int*   stage    = (int*)(ws + off);   off += align256((size_t)nbuckets * BCAP * 4);
    unsigned short* w1bt = (unsigned short*)(ws + off); off += align256((size_t)HID * NFEAT * 2);
    __hip_bfloat16* t1 = (__hip_bfloat16*)(ws + off); off += align256((size_t)(n + 1) * HID * 2);
    __hip_bfloat16* t2 = (__hip_bfloat16*)(ws + off); off += align256((size_t)(n + 1) * T2STRIDE * 2);

    (void)hipMemsetAsync(bcursor, 0, 256 * 4, stream);
    (void)hipMemsetAsync(t1 + (size_t)n * HID, 0, HID * 2, stream);           // sentinel zero row
    (void)hipMemsetAsync(t2 + (size_t)n * T2STRIDE, 0, T2STRIDE * 2, stream); // sentinel zero row
    w1_to_bf16t<<<(HID * NFEAT) / 256, 256, 0, stream>>>(W1, w1bt);
    bin_scatter<<<(e + CHUNK - 1) / CHUNK, 256, 0, stream>>>(ei, e, nbuckets, bcursor, stage);
    bucket_csr<<<nbuckets, 256, 0, stream>>>(stage, bcursor, row_ptr, dinv, col, n, e, nbuckets);
    gemm1<<<(n + 63) / 64, 256, 0, stream>>>(x, w1bt, dinv, t1, n);
    agg1_gemm2<<<(n + 3) / 4, 256, 0, stream>>>(t1, row_ptr, col, dinv, b1, W2, t2, n);
    agg2_softmax<<<(n + 3) / 4, 256, 0, stream>>>(t2, row_ptr, col, dinv, b2, out, n);
}